// Round 12
// baseline (157.481 us; speedup 1.0000x reference)
//
#include <hip/hip_runtime.h>

#define BB 64
#define SC 640
#define SN 128
#define DD 768
#define CODE_DEF 254
#define NL_DEF 126

typedef short bf16x8 __attribute__((ext_vector_type(8)));
typedef float f32x4 __attribute__((ext_vector_type(4)));

__device__ __forceinline__ unsigned short f2bf(float f) {
  unsigned u = __float_as_uint(f);
  u += 0x7fffu + ((u >> 16) & 1u);  // round-to-nearest-even
  return (unsigned short)(u >> 16);
}

// ---------------- K2: node-avg GEMM, fully self-sufficient (R11 proven) ------
__global__ __launch_bounds__(256) void k2_mfma(
    const int* __restrict__ code_ids, const int* __restrict__ nl_ids,
    const int* __restrict__ attn, const int* __restrict__ pos,
    const float* __restrict__ Wemb, float* __restrict__ codeh,
    int* __restrict__ len_code, int* __restrict__ len_nl) {
  __shared__ unsigned short As[2][64 * 64];
  __shared__ unsigned short Bs[2][128 * 64];
  __shared__ int rowsidx[64];
  __shared__ int cid[SC];
  __shared__ unsigned long long tokm[10];
  __shared__ float cnts_l[64];
  __shared__ int cnt_s, flag_s;
  int id = blockIdx.x;
  int b = id & 63;   // same-b -> same XCD (stride 64)
  int g = id >> 6;   // 0..23
  int nt = g & 3, dt = g >> 2;  // 4 node-tiles x 6 d-tiles
  int tid = threadIdx.x;
  const int lane = tid & 63, w = tid >> 6, wm = w >> 1, wn = w & 1;
  for (int i = tid; i < SC; i += 256) cid[i] = code_ids[b * SC + i];
  if (tid < 64) rowsidx[tid] = -1;  // w0's own lanes, program-order safe
  if (w == 0) {  // node compaction, keep slots in [nt*64, nt*64+64)
    int base = 0;
    for (int c = 0; c < 10; ++c) {
      bool isn = pos[b * SC + c * 64 + lane] == 0;
      unsigned long long m = __ballot(isn);
      int pre = __popcll(m & ((1ull << lane) - 1ull));
      int slot = base + pre;
      if (isn && slot >= nt * 64 && slot < nt * 64 + 64)
        rowsidx[slot - nt * 64] = c * 64 + lane;
      base += __popcll(m);
    }
    if (lane == 0) cnt_s = base;
  } else if (w == 1) {  // token-mask bits
    for (int k = 0; k < 10; ++k) {
      unsigned long long m = __ballot(pos[b * SC + k * 64 + lane] >= 2);
      if (lane == 0) tokm[k] = m;
    }
  } else if (w == 2) {  // attn dtype detect (first 4KB, L2-hot)
    int bad = 0;
    for (int i = lane; i < 1024; i += 64)
      if (((const unsigned*)attn)[i] > 1u) bad = 1;
    unsigned long long m = __ballot(bad);
    if (lane == 0) flag_s = (m != 0ull) ? 1 : 0;
  } else if (g == 0) {  // w==3: eos lens for k34 (one block-set per batch)
    int first = CODE_DEF;
    for (int c = 0; c < SC; c += 64) {
      unsigned long long m = __ballot(code_ids[b * SC + c + lane] == 2);
      if (m) { first = c + __builtin_ctzll(m); break; }
    }
    int firstn = NL_DEF;
    for (int c = 0; c < SN; c += 64) {
      unsigned long long m = __ballot(nl_ids[b * SN + c + lane] == 2);
      if (m) { firstn = c + __builtin_ctzll(m); break; }
    }
    if (lane == 0) { len_code[b] = first; len_nl[b] = firstn; }
  }
  __syncthreads();
  const int count = cnt_s;
  if (nt * 64 >= count) return;
  const int dcol = dt * 128;
  const int isu8 = flag_s;

  f32x4 acc[2][4];
#pragma unroll
  for (int m = 0; m < 2; ++m)
#pragma unroll
    for (int n = 0; n < 4; ++n) acc[m][n] = (f32x4){0.f, 0.f, 0.f, 0.f};

  const int r_a = tid >> 2, q_ = tid & 3;  // A: row 0..63, 16-t quarter 0..3
  const int nrow_a = rowsidx[r_a];
  const long arow = (nrow_a >= 0) ? ((long)b * SC + nrow_a) * SC : 0;
  const unsigned char* attn_u8 = (const unsigned char*)attn;
  int ptot = 0;
  int tg4[2], d0[2];
#pragma unroll
  for (int q = 0; q < 2; ++q) {
    int task = tid + 256 * q;
    tg4[q] = task >> 5;       // 0..15
    d0[q] = (task & 31) * 4;  // 0..124
  }

  f32x4 va[2][4];
  unsigned bits16;

#define LOADC(cc)                                                          \
  {                                                                        \
    unsigned tokq = (unsigned)((tokm[cc] >> (q_ * 16)) & 0xffffull);       \
    unsigned ab = 0;                                                       \
    if (nrow_a >= 0) {                                                     \
      if (isu8) {                                                          \
        uint4 v = *(const uint4*)(attn_u8 + arow + (cc) * 64 + q_ * 16);   \
        _Pragma("unroll") for (int j = 0; j < 4; ++j) {                    \
          ab |= (((v.x >> (8 * j)) & 0xffu) ? 1u : 0u) << j;               \
          ab |= (((v.y >> (8 * j)) & 0xffu) ? 1u : 0u) << (4 + j);         \
          ab |= (((v.z >> (8 * j)) & 0xffu) ? 1u : 0u) << (8 + j);         \
          ab |= (((v.w >> (8 * j)) & 0xffu) ? 1u : 0u) << (12 + j);        \
        }                                                                  \
      } else {                                                             \
        const int* ap = attn + arow + (cc) * 64 + q_ * 16;                 \
        _Pragma("unroll") for (int j = 0; j < 4; ++j) {                    \
          int4 v = *(const int4*)(ap + j * 4);                             \
          ab |= (v.x ? 1u : 0u) << (4 * j);                                \
          ab |= (v.y ? 1u : 0u) << (4 * j + 1);                            \
          ab |= (v.z ? 1u : 0u) << (4 * j + 2);                            \
          ab |= (v.w ? 1u : 0u) << (4 * j + 3);                            \
        }                                                                  \
      }                                                                    \
    }                                                                      \
    bits16 = ab & tokq;                                                    \
    ptot += __popc(bits16);                                                \
    _Pragma("unroll") for (int q = 0; q < 2; ++q)                          \
        _Pragma("unroll") for (int j = 0; j < 4; ++j) va[q][j] =           \
        *(const f32x4*)(Wemb +                                             \
                        (long)cid[(cc) * 64 + tg4[q] * 4 + j] * DD +       \
                        dcol + d0[q]);                                     \
  }

#define WRITEB(bf_)                                                        \
  {                                                                        \
    unsigned short* Ab = As[bf_];                                          \
    unsigned short* Bb = Bs[bf_];                                          \
    int tl = q_ * 16, sw = (r_a & 7) << 3;                                 \
    bf16x8 u0, u1;                                                         \
    _Pragma("unroll") for (int j = 0; j < 8; ++j) {                        \
      u0[j] = ((bits16 >> j) & 1u) ? (short)0x3F80 : (short)0;             \
      u1[j] = ((bits16 >> (8 + j)) & 1u) ? (short)0x3F80 : (short)0;       \
    }                                                                      \
    *(bf16x8*)(&Ab[r_a * 64 + (tl ^ sw)]) = u0;                            \
    *(bf16x8*)(&Ab[r_a * 64 + ((tl + 8) ^ sw)]) = u1;                      \
    _Pragma("unroll") for (int q = 0; q < 2; ++q)                          \
        _Pragma("unroll") for (int dj = 0; dj < 4; ++dj) {                 \
      int d = d0[q] + dj;                                                  \
      ushort4 u = {f2bf(va[q][0][dj]), f2bf(va[q][1][dj]),                 \
                   f2bf(va[q][2][dj]), f2bf(va[q][3][dj])};                \
      int s = ((((d >> 2) & 7) ^ ((d & 3) << 1)) << 3);                    \
      *(ushort4*)(&Bb[d * 64 + ((tg4[q] * 4) ^ s)]) = u;                   \
    }                                                                      \
  }

#define MFMAP(bf_)                                                         \
  {                                                                        \
    const unsigned short* Ab = As[bf_];                                    \
    const unsigned short* Bb = Bs[bf_];                                    \
    _Pragma("unroll") for (int ks = 0; ks < 2; ++ks) {                     \
      int kb = ks * 32 + (lane >> 4) * 8;                                  \
      bf16x8 af[2], bfv[4];                                                \
      _Pragma("unroll") for (int m = 0; m < 2; ++m) {                      \
        int rr = wm * 32 + m * 16 + (lane & 15);                           \
        af[m] = *(const bf16x8*)(&Ab[rr * 64 + (kb ^ ((rr & 7) << 3))]);   \
      }                                                                    \
      _Pragma("unroll") for (int n = 0; n < 4; ++n) {                      \
        int cc = wn * 64 + n * 16 + (lane & 15);                           \
        int s = ((((cc >> 2) & 7) ^ ((cc & 3) << 1)) << 3);                \
        bfv[n] = *(const bf16x8*)(&Bb[cc * 64 + (kb ^ s)]);                \
      }                                                                    \
      _Pragma("unroll") for (int m = 0; m < 2; ++m)                        \
          _Pragma("unroll") for (int n = 0; n < 4; ++n) acc[m][n] =        \
          __builtin_amdgcn_mfma_f32_16x16x32_bf16(af[m], bfv[n],           \
                                                  acc[m][n], 0, 0, 0);     \
    }                                                                      \
  }

  LOADC(0);
  WRITEB(0);
  __syncthreads();
  for (int c = 0; c < 10; ++c) {
    if (c < 9) LOADC(c + 1);
    MFMAP(c & 1);
    if (c < 9) WRITEB((c + 1) & 1);
    __syncthreads();
  }

  {
    int t4 = ptot + __shfl_xor(ptot, 1, 64);
    t4 += __shfl_xor(t4, 2, 64);
    if (q_ == 0) cnts_l[r_a] = (float)t4;
  }
  __syncthreads();

  float* outb = codeh + (long)b * SC * DD + dcol + wn * 64;
#pragma unroll
  for (int m = 0; m < 2; ++m) {
    int row0 = wm * 32 + m * 16 + ((lane >> 4) << 2);
#pragma unroll
    for (int rr2 = 0; rr2 < 4; ++rr2) {
      int slotr = row0 + rr2;
      int nr = rowsidx[slotr];
      if (nr < 0) continue;
      float cnt = cnts_l[slotr];
      float inv = (cnt > 0.f) ? 1.f / cnt : 0.f;
      float* orow = outb + (long)nr * DD;
#pragma unroll
      for (int n = 0; n < 4; ++n)
        orow[n * 16 + (lane & 15)] = acc[m][n][rr2] * inv;
    }
  }
#undef LOADC
#undef WRITEB
#undef MFMAP
}

// ---------------- K34: fused finish, 2 rows per wave (ILP x2) ----------------
#define CODE_BLOCKS2 (BB * SC / 8)
__global__ __launch_bounds__(256) void k34_fused(
    const int* __restrict__ code_ids, const int* __restrict__ pos,
    const float* __restrict__ Wemb, float* __restrict__ codeh,
    const int* __restrict__ roles, const float* __restrict__ role_table,
    const float* __restrict__ w_code, const float* __restrict__ b_code,
    const int* __restrict__ len_code, float* __restrict__ code_probs,
    const int* __restrict__ nl_ids, const float* __restrict__ w_nl,
    const float* __restrict__ b_nl, const int* __restrict__ len_nl,
    float* __restrict__ nlh, float* __restrict__ nl_probs) {
  int w = threadIdx.x >> 6, lane = threadIdx.x & 63;
  if (blockIdx.x < CODE_BLOCKS2) {
    long row0 = (long)blockIdx.x * 8 + w * 2;  // this wave: rows row0, row0+1
    float* rp0 = codeh + row0 * DD;
    float* rp1 = rp0 + DD;
    const float* s0 =
        (pos[row0] == 0) ? rp0 : (Wemb + (long)code_ids[row0] * DD);
    const float* s1 =
        (pos[row0 + 1] == 0) ? rp1 : (Wemb + (long)code_ids[row0 + 1] * DD);
    f32x4 x0[3], x1[3];
#pragma unroll
    for (int j = 0; j < 3; ++j) {
      x0[j] = *(const f32x4*)(s0 + lane * 4 + j * 256);
      x1[j] = *(const f32x4*)(s1 + lane * 4 + j * 256);
    }
    float ss0 = 0.f, ss1 = 0.f;
#pragma unroll
    for (int j = 0; j < 3; ++j)
#pragma unroll
      for (int e = 0; e < 4; ++e) {
        ss0 += x0[j][e] * x0[j][e];
        ss1 += x1[j][e] * x1[j][e];
      }
#pragma unroll
    for (int o = 32; o > 0; o >>= 1) {
      ss0 += __shfl_xor(ss0, o, 64);
      ss1 += __shfl_xor(ss1, o, 64);
    }
    float inv0 = 1.f / fmaxf(sqrtf(ss0), 1e-12f);
    float inv1 = 1.f / fmaxf(sqrtf(ss1), 1e-12f);
    const float* rt0 = role_table + (long)roles[row0] * DD;
    const float* rt1 = role_table + (long)roles[row0 + 1] * DD;
    float dot0 = 0.f, dot1 = 0.f;
#pragma unroll
    for (int j = 0; j < 3; ++j) {
      f32x4 r0 = *(const f32x4*)(rt0 + lane * 4 + j * 256);
      f32x4 r1 = *(const f32x4*)(rt1 + lane * 4 + j * 256);
      f32x4 wc = *(const f32x4*)(w_code + lane * 4 + j * 256);
      f32x4 y0, y1;
#pragma unroll
      for (int e = 0; e < 4; ++e) {
        y0[e] = x0[j][e] * inv0;
        y1[e] = x1[j][e] * inv1;
        dot0 += (y0[e] + r0[e]) * wc[e];
        dot1 += (y1[e] + r1[e]) * wc[e];
      }
      *(f32x4*)(rp0 + lane * 4 + j * 256) = y0;
      *(f32x4*)(rp1 + lane * 4 + j * 256) = y1;
    }
#pragma unroll
    for (int o = 32; o > 0; o >>= 1) {
      dot0 += __shfl_xor(dot0, o, 64);
      dot1 += __shfl_xor(dot1, o, 64);
    }
    if (lane == 0) {
      int b = (int)(row0 / SC);
      int s = (int)(row0 % SC);
      int lc = len_code[b];
      float bc = b_code[0];
      float p0 = 1.f / (1.f + expf(-(dot0 + bc)));
      float p1 = 1.f / (1.f + expf(-(dot1 + bc)));
      code_probs[row0] = (s < lc) ? p0 : 0.f;
      code_probs[row0 + 1] = (s + 1 < lc) ? p1 : 0.f;
    }
  } else {
    long row0 = (long)(blockIdx.x - CODE_BLOCKS2) * 8 + w * 2;
    const float* s0 = Wemb + (long)nl_ids[row0] * DD;
    const float* s1 = Wemb + (long)nl_ids[row0 + 1] * DD;
    f32x4 x0[3], x1[3];
#pragma unroll
    for (int j = 0; j < 3; ++j) {
      x0[j] = *(const f32x4*)(s0 + lane * 4 + j * 256);
      x1[j] = *(const f32x4*)(s1 + lane * 4 + j * 256);
    }
    float ss0 = 0.f, ss1 = 0.f;
#pragma unroll
    for (int j = 0; j < 3; ++j)
#pragma unroll
      for (int e = 0; e < 4; ++e) {
        ss0 += x0[j][e] * x0[j][e];
        ss1 += x1[j][e] * x1[j][e];
      }
#pragma unroll
    for (int o = 32; o > 0; o >>= 1) {
      ss0 += __shfl_xor(ss0, o, 64);
      ss1 += __shfl_xor(ss1, o, 64);
    }
    float inv0 = 1.f / fmaxf(sqrtf(ss0), 1e-12f);
    float inv1 = 1.f / fmaxf(sqrtf(ss1), 1e-12f);
    float* o0 = nlh + row0 * DD;
    float* o1 = o0 + DD;
    float dot0 = 0.f, dot1 = 0.f;
#pragma unroll
    for (int j = 0; j < 3; ++j) {
      f32x4 wn = *(const f32x4*)(w_nl + lane * 4 + j * 256);
      f32x4 y0, y1;
#pragma unroll
      for (int e = 0; e < 4; ++e) {
        y0[e] = x0[j][e] * inv0;
        y1[e] = x1[j][e] * inv1;
        dot0 += y0[e] * wn[e];
        dot1 += y1[e] * wn[e];
      }
      *(f32x4*)(o0 + lane * 4 + j * 256) = y0;
      *(f32x4*)(o1 + lane * 4 + j * 256) = y1;
    }
#pragma unroll
    for (int o = 32; o > 0; o >>= 1) {
      dot0 += __shfl_xor(dot0, o, 64);
      dot1 += __shfl_xor(dot1, o, 64);
    }
    if (lane == 0) {
      int b = (int)(row0 / SN);
      int s = (int)(row0 % SN);
      int ln = len_nl[b];
      float bn = b_nl[0];
      float p0 = 1.f / (1.f + expf(-(dot0 + bn)));
      float p1 = 1.f / (1.f + expf(-(dot1 + bn)));
      nl_probs[row0] = (s < ln) ? p0 : 0.f;
      nl_probs[row0 + 1] = (s + 1 < ln) ? p1 : 0.f;
    }
  }
}

// ---------------- K5: sim via bf16 MFMA, 64x128 tiles, KC=64 (R9 proven) -----
__global__ __launch_bounds__(256) void k5_mfma(const float* __restrict__ nlh,
                                               const float* __restrict__ codeh,
                                               float* __restrict__ sim) {
  __shared__ unsigned short As[64 * 64];
  __shared__ unsigned short Bs[128 * 64];
  int id = blockIdx.x;
  int b = id & 63;
  int r = id >> 6;             // 0..9
  int nt = r % 2, ct = r / 2;  // nl half, code 128-tile
  int tid = threadIdx.x;
  int lane = tid & 63;
  int w = tid >> 6;
  int wm = w >> 1, wn = w & 1;  // wave: 32 nl x 64 code

  f32x4 acc[2][4];
#pragma unroll
  for (int m = 0; m < 2; ++m)
#pragma unroll
    for (int n = 0; n < 4; ++n) acc[m][n] = (f32x4){0.f, 0.f, 0.f, 0.f};

  const float* Ag = nlh + ((long)b * SN + nt * 64) * DD;
  const float* Bg = codeh + ((long)b * SC + ct * 128) * DD;

  for (int c = 0; c < DD / 64; ++c) {
#pragma unroll
    for (int it = 0; it < 4; ++it) {
      int i = tid + 256 * it;  // 0..1023
      int row = i >> 4, k0 = (i & 15) * 4;
      float4 va = *(const float4*)(Ag + (long)row * DD + c * 64 + k0);
      ushort4 ua = {f2bf(va.x), f2bf(va.y), f2bf(va.z), f2bf(va.w)};
      *(ushort4*)(&As[row * 64 + (k0 ^ ((row & 7) << 3))]) = ua;
    }
#pragma unroll
    for (int it = 0; it < 8; ++it) {
      int i = tid + 256 * it;  // 0..2047
      int row = i >> 4, k0 = (i & 15) * 4;
      float4 vb = *(const float4*)(Bg + (long)row * DD + c * 64 + k0);
      ushort4 ub = {f2bf(vb.x), f2bf(vb.y), f2bf(vb.z), f2bf(vb.w)};
      *(ushort4*)(&Bs[row * 64 + (k0 ^ ((row & 7) << 3))]) = ub;
    }
    __syncthreads();
#pragma unroll
    for (int ks = 0; ks < 2; ++ks) {
      int kb = ks * 32 + (lane >> 4) * 8;
      bf16x8 af[2], bfr[4];
#pragma unroll
      for (int m = 0; m < 2; ++m) {
        int rr = wm * 32 + m * 16 + (lane & 15);
        af[m] = *(const bf16x8*)(&As[rr * 64 + (kb ^ ((rr & 7) << 3))]);
      }
#pragma unroll
      for (int n = 0; n < 4; ++n) {
        int rr = wn * 64 + n * 16 + (lane & 15);
        bfr[n] = *(const bf16x8*)(&Bs[rr * 64 + (kb ^ ((rr & 7) << 3))]);
      }
#pragma unroll
      for (int m = 0; m < 2; ++m)
#pragma unroll
        for (int n = 0; n < 4; ++n)
          acc[m][n] = __builtin_amdgcn_mfma_f32_16x16x32_bf16(
              af[m], bfr[n], acc[m][n], 0, 0, 0);
    }
    __syncthreads();
  }
  long ob = ((long)b * SN + nt * 64) * SC + ct * 128;
#pragma unroll
  for (int m = 0; m < 2; ++m) {
    int row0 = wm * 32 + m * 16 + ((lane >> 4) << 2);
#pragma unroll
    for (int n = 0; n < 4; ++n) {
      int col = wn * 64 + n * 16 + (lane & 15);
#pragma unroll
      for (int rr = 0; rr < 4; ++rr)
        sim[ob + (long)(row0 + rr) * SC + col] = acc[m][n][rr];
    }
  }
}

// ---------------- launcher ---------------------------------------------------
extern "C" void kernel_launch(void* const* d_in, const int* in_sizes, int n_in,
                              void* d_out, int out_size, void* d_ws,
                              size_t ws_size, hipStream_t stream) {
  const int* code_ids = (const int*)d_in[0];
  const int* attn = (const int*)d_in[1];
  const int* pos = (const int*)d_in[2];
  const int* nl_ids = (const int*)d_in[3];
  const int* roles = (const int*)d_in[4];
  const float* Wemb = (const float*)d_in[5];
  const float* role_table = (const float*)d_in[6];
  const float* w_code = (const float*)d_in[7];
  const float* b_code = (const float*)d_in[8];
  const float* w_nl = (const float*)d_in[9];
  const float* b_nl = (const float*)d_in[10];

  float* out = (float*)d_out;
  float* codeh = out;                  // 64*640*768
  float* code_probs = out + 31457280;  // 64*640
  float* nlh = out + 31498240;         // 64*128*768
  float* nl_probs = out + 37789696;    // 64*128
  float* sim = out + 37797888;         // 64*128*640

  int* wsi = (int*)d_ws;
  int* len_code = wsi;       // 64
  int* len_nl = wsi + 64;    // 64

  k2_mfma<<<BB * 24, 256, 0, stream>>>(code_ids, nl_ids, attn, pos, Wemb,
                                       codeh, len_code, len_nl);
  k34_fused<<<CODE_BLOCKS2 + BB * SN / 8, 256, 0, stream>>>(
      code_ids, pos, Wemb, codeh, roles, role_table, w_code, b_code, len_code,
      code_probs, nl_ids, w_nl, b_nl, len_nl, nlh, nl_probs);
  k5_mfma<<<BB * 10, 256, 0, stream>>>(nlh, codeh, sim);
}

// Round 13
// 146.747 us; speedup vs baseline: 1.0731x; 1.0731x over previous
//
#include <hip/hip_runtime.h>

#define BB 64
#define SC 640
#define SN 128
#define DD 768
#define CODE_DEF 254
#define NL_DEF 126

typedef short bf16x8 __attribute__((ext_vector_type(8)));
typedef float f32x4 __attribute__((ext_vector_type(4)));

__device__ __forceinline__ unsigned short f2bf(float f) {
  unsigned u = __float_as_uint(f);
  u += 0x7fffu + ((u >> 16) & 1u);  // round-to-nearest-even
  return (unsigned short)(u >> 16);
}

#define K2_BLOCKS (BB * 24)

// ---------------- K2: node-avg GEMM + appended nl-branch blocks --------------
// Blocks [0, BB*24): R11-proven node-avg MFMA GEMM (self-sufficient prologue).
// Blocks [BB*24, BB*24 + BB*SN/4): nl branch, 1 row/wave, len_nl computed
// locally (no inter-block ordering assumed). Overlaps k2's tail.
__global__ __launch_bounds__(256) void k2_mfma(
    const int* __restrict__ code_ids, const int* __restrict__ nl_ids,
    const int* __restrict__ attn, const int* __restrict__ pos,
    const float* __restrict__ Wemb, float* __restrict__ codeh,
    int* __restrict__ len_code, const float* __restrict__ w_nl,
    const float* __restrict__ b_nl, float* __restrict__ nlh,
    float* __restrict__ nl_probs) {
  int id = blockIdx.x;
  if (id >= K2_BLOCKS) {  // ---------------- nl branch ----------------
    int w = threadIdx.x >> 6, lane = threadIdx.x & 63;
    long row = (long)(id - K2_BLOCKS) * 4 + w;
    int b = (int)(row / SN), s = (int)(row % SN);
    int firstn = NL_DEF;
    for (int c = 0; c < SN; c += 64) {
      unsigned long long m = __ballot(nl_ids[b * SN + c + lane] == 2);
      if (m) { firstn = c + __builtin_ctzll(m); break; }
    }
    const float* src = Wemb + (long)nl_ids[row] * DD;
    f32x4 x[3];
#pragma unroll
    for (int j = 0; j < 3; ++j)
      x[j] = *(const f32x4*)(src + lane * 4 + j * 256);
    float ss = 0.f;
#pragma unroll
    for (int j = 0; j < 3; ++j)
#pragma unroll
      for (int e = 0; e < 4; ++e) ss += x[j][e] * x[j][e];
#pragma unroll
    for (int o = 32; o > 0; o >>= 1) ss += __shfl_xor(ss, o, 64);
    float inv = 1.f / fmaxf(sqrtf(ss), 1e-12f);
    float* o = nlh + row * DD;
    float dot = 0.f;
#pragma unroll
    for (int j = 0; j < 3; ++j) {
      f32x4 wn = *(const f32x4*)(w_nl + lane * 4 + j * 256);
      f32x4 y;
#pragma unroll
      for (int e = 0; e < 4; ++e) {
        y[e] = x[j][e] * inv;
        dot += y[e] * wn[e];
      }
      *(f32x4*)(o + lane * 4 + j * 256) = y;
    }
#pragma unroll
    for (int of = 32; of > 0; of >>= 1) dot += __shfl_xor(dot, of, 64);
    if (lane == 0) {
      float p = 1.f / (1.f + expf(-(dot + b_nl[0])));
      nl_probs[row] = (s < firstn) ? p : 0.f;
    }
    return;
  }
  // ---------------- node-avg GEMM (R11 proven) ----------------
  __shared__ unsigned short As[2][64 * 64];
  __shared__ unsigned short Bs[2][128 * 64];
  __shared__ int rowsidx[64];
  __shared__ int cid[SC];
  __shared__ unsigned long long tokm[10];
  __shared__ float cnts_l[64];
  __shared__ int cnt_s, flag_s;
  int b = id & 63;   // same-b -> same XCD (stride 64)
  int g = id >> 6;   // 0..23
  int nt = g & 3, dt = g >> 2;  // 4 node-tiles x 6 d-tiles
  int tid = threadIdx.x;
  const int lane = tid & 63, w = tid >> 6, wm = w >> 1, wn = w & 1;
  for (int i = tid; i < SC; i += 256) cid[i] = code_ids[b * SC + i];
  if (tid < 64) rowsidx[tid] = -1;  // w0's own lanes, program-order safe
  if (w == 0) {  // node compaction, keep slots in [nt*64, nt*64+64)
    int base = 0;
    for (int c = 0; c < 10; ++c) {
      bool isn = pos[b * SC + c * 64 + lane] == 0;
      unsigned long long m = __ballot(isn);
      int pre = __popcll(m & ((1ull << lane) - 1ull));
      int slot = base + pre;
      if (isn && slot >= nt * 64 && slot < nt * 64 + 64)
        rowsidx[slot - nt * 64] = c * 64 + lane;
      base += __popcll(m);
    }
    if (lane == 0) cnt_s = base;
  } else if (w == 1) {  // token-mask bits
    for (int k = 0; k < 10; ++k) {
      unsigned long long m = __ballot(pos[b * SC + k * 64 + lane] >= 2);
      if (lane == 0) tokm[k] = m;
    }
  } else if (w == 2) {  // attn dtype detect (first 4KB, L2-hot)
    int bad = 0;
    for (int i = lane; i < 1024; i += 64)
      if (((const unsigned*)attn)[i] > 1u) bad = 1;
    unsigned long long m = __ballot(bad);
    if (lane == 0) flag_s = (m != 0ull) ? 1 : 0;
  } else if (g == 0) {  // w==3: eos len for k34 code branch
    int first = CODE_DEF;
    for (int c = 0; c < SC; c += 64) {
      unsigned long long m = __ballot(code_ids[b * SC + c + lane] == 2);
      if (m) { first = c + __builtin_ctzll(m); break; }
    }
    if (lane == 0) len_code[b] = first;
  }
  __syncthreads();
  const int count = cnt_s;
  if (nt * 64 >= count) return;
  const int dcol = dt * 128;
  const int isu8 = flag_s;

  f32x4 acc[2][4];
#pragma unroll
  for (int m = 0; m < 2; ++m)
#pragma unroll
    for (int n = 0; n < 4; ++n) acc[m][n] = (f32x4){0.f, 0.f, 0.f, 0.f};

  const int r_a = tid >> 2, q_ = tid & 3;  // A: row 0..63, 16-t quarter 0..3
  const int nrow_a = rowsidx[r_a];
  const long arow = (nrow_a >= 0) ? ((long)b * SC + nrow_a) * SC : 0;
  const unsigned char* attn_u8 = (const unsigned char*)attn;
  int ptot = 0;
  int tg4[2], d0[2];
#pragma unroll
  for (int q = 0; q < 2; ++q) {
    int task = tid + 256 * q;
    tg4[q] = task >> 5;       // 0..15
    d0[q] = (task & 31) * 4;  // 0..124
  }

  f32x4 va[2][4];
  unsigned bits16;

#define LOADC(cc)                                                          \
  {                                                                        \
    unsigned tokq = (unsigned)((tokm[cc] >> (q_ * 16)) & 0xffffull);       \
    unsigned ab = 0;                                                       \
    if (nrow_a >= 0) {                                                     \
      if (isu8) {                                                          \
        uint4 v = *(const uint4*)(attn_u8 + arow + (cc) * 64 + q_ * 16);   \
        _Pragma("unroll") for (int j = 0; j < 4; ++j) {                    \
          ab |= (((v.x >> (8 * j)) & 0xffu) ? 1u : 0u) << j;               \
          ab |= (((v.y >> (8 * j)) & 0xffu) ? 1u : 0u) << (4 + j);         \
          ab |= (((v.z >> (8 * j)) & 0xffu) ? 1u : 0u) << (8 + j);         \
          ab |= (((v.w >> (8 * j)) & 0xffu) ? 1u : 0u) << (12 + j);        \
        }                                                                  \
      } else {                                                             \
        const int* ap = attn + arow + (cc) * 64 + q_ * 16;                 \
        _Pragma("unroll") for (int j = 0; j < 4; ++j) {                    \
          int4 v = *(const int4*)(ap + j * 4);                             \
          ab |= (v.x ? 1u : 0u) << (4 * j);                                \
          ab |= (v.y ? 1u : 0u) << (4 * j + 1);                            \
          ab |= (v.z ? 1u : 0u) << (4 * j + 2);                            \
          ab |= (v.w ? 1u : 0u) << (4 * j + 3);                            \
        }                                                                  \
      }                                                                    \
    }                                                                      \
    bits16 = ab & tokq;                                                    \
    ptot += __popc(bits16);                                                \
    _Pragma("unroll") for (int q = 0; q < 2; ++q)                          \
        _Pragma("unroll") for (int j = 0; j < 4; ++j) va[q][j] =           \
        *(const f32x4*)(Wemb +                                             \
                        (long)cid[(cc) * 64 + tg4[q] * 4 + j] * DD +       \
                        dcol + d0[q]);                                     \
  }

#define WRITEB(bf_)                                                        \
  {                                                                        \
    unsigned short* Ab = As[bf_];                                          \
    unsigned short* Bb = Bs[bf_];                                          \
    int tl = q_ * 16, sw = (r_a & 7) << 3;                                 \
    bf16x8 u0, u1;                                                         \
    _Pragma("unroll") for (int j = 0; j < 8; ++j) {                        \
      u0[j] = ((bits16 >> j) & 1u) ? (short)0x3F80 : (short)0;             \
      u1[j] = ((bits16 >> (8 + j)) & 1u) ? (short)0x3F80 : (short)0;       \
    }                                                                      \
    *(bf16x8*)(&Ab[r_a * 64 + (tl ^ sw)]) = u0;                            \
    *(bf16x8*)(&Ab[r_a * 64 + ((tl + 8) ^ sw)]) = u1;                      \
    _Pragma("unroll") for (int q = 0; q < 2; ++q)                          \
        _Pragma("unroll") for (int dj = 0; dj < 4; ++dj) {                 \
      int d = d0[q] + dj;                                                  \
      ushort4 u = {f2bf(va[q][0][dj]), f2bf(va[q][1][dj]),                 \
                   f2bf(va[q][2][dj]), f2bf(va[q][3][dj])};                \
      int s = ((((d >> 2) & 7) ^ ((d & 3) << 1)) << 3);                    \
      *(ushort4*)(&Bb[d * 64 + ((tg4[q] * 4) ^ s)]) = u;                   \
    }                                                                      \
  }

#define MFMAP(bf_)                                                         \
  {                                                                        \
    const unsigned short* Ab = As[bf_];                                    \
    const unsigned short* Bb = Bs[bf_];                                    \
    _Pragma("unroll") for (int ks = 0; ks < 2; ++ks) {                     \
      int kb = ks * 32 + (lane >> 4) * 8;                                  \
      bf16x8 af[2], bfv[4];                                                \
      _Pragma("unroll") for (int m = 0; m < 2; ++m) {                      \
        int rr = wm * 32 + m * 16 + (lane & 15);                           \
        af[m] = *(const bf16x8*)(&Ab[rr * 64 + (kb ^ ((rr & 7) << 3))]);   \
      }                                                                    \
      _Pragma("unroll") for (int n = 0; n < 4; ++n) {                      \
        int cc = wn * 64 + n * 16 + (lane & 15);                           \
        int s = ((((cc >> 2) & 7) ^ ((cc & 3) << 1)) << 3);                \
        bfv[n] = *(const bf16x8*)(&Bb[cc * 64 + (kb ^ s)]);                \
      }                                                                    \
      _Pragma("unroll") for (int m = 0; m < 2; ++m)                        \
          _Pragma("unroll") for (int n = 0; n < 4; ++n) acc[m][n] =        \
          __builtin_amdgcn_mfma_f32_16x16x32_bf16(af[m], bfv[n],           \
                                                  acc[m][n], 0, 0, 0);     \
    }                                                                      \
  }

  LOADC(0);
  WRITEB(0);
  __syncthreads();
  for (int c = 0; c < 10; ++c) {
    if (c < 9) LOADC(c + 1);
    MFMAP(c & 1);
    if (c < 9) WRITEB((c + 1) & 1);
    __syncthreads();
  }

  {
    int t4 = ptot + __shfl_xor(ptot, 1, 64);
    t4 += __shfl_xor(t4, 2, 64);
    if (q_ == 0) cnts_l[r_a] = (float)t4;
  }
  __syncthreads();

  float* outb = codeh + (long)b * SC * DD + dcol + wn * 64;
#pragma unroll
  for (int m = 0; m < 2; ++m) {
    int row0 = wm * 32 + m * 16 + ((lane >> 4) << 2);
#pragma unroll
    for (int rr2 = 0; rr2 < 4; ++rr2) {
      int slotr = row0 + rr2;
      int nr = rowsidx[slotr];
      if (nr < 0) continue;
      float cnt = cnts_l[slotr];
      float inv = (cnt > 0.f) ? 1.f / cnt : 0.f;
      float* orow = outb + (long)nr * DD;
#pragma unroll
      for (int n = 0; n < 4; ++n)
        orow[n * 16 + (lane & 15)] = acc[m][n][rr2] * inv;
    }
  }
#undef LOADC
#undef WRITEB
#undef MFMAP
}

// ---------------- K34: code-finish only, 1 row per wave (R11 proven) ---------
#define CODE_BLOCKS (BB * SC / 4)
__global__ __launch_bounds__(256) void k34_fused(
    const int* __restrict__ code_ids, const int* __restrict__ pos,
    const float* __restrict__ Wemb, float* __restrict__ codeh,
    const int* __restrict__ roles, const float* __restrict__ role_table,
    const float* __restrict__ w_code, const float* __restrict__ b_code,
    const int* __restrict__ len_code, float* __restrict__ code_probs) {
  int w = threadIdx.x >> 6, lane = threadIdx.x & 63;
  long row = (long)blockIdx.x * 4 + w;
  int b = (int)(row / SC), s = (int)(row % SC);
  float* rp = codeh + row * DD;
  const float* src = (pos[row] == 0) ? rp : (Wemb + (long)code_ids[row] * DD);
  f32x4 x[3];
#pragma unroll
  for (int j = 0; j < 3; ++j)
    x[j] = *(const f32x4*)(src + lane * 4 + j * 256);
  float ss = 0.f;
#pragma unroll
  for (int j = 0; j < 3; ++j)
#pragma unroll
    for (int e = 0; e < 4; ++e) ss += x[j][e] * x[j][e];
#pragma unroll
  for (int o = 32; o > 0; o >>= 1) ss += __shfl_xor(ss, o, 64);
  float inv = 1.f / fmaxf(sqrtf(ss), 1e-12f);
  const float* rt = role_table + (long)roles[row] * DD;
  float dot = 0.f;
#pragma unroll
  for (int j = 0; j < 3; ++j) {
    f32x4 r = *(const f32x4*)(rt + lane * 4 + j * 256);
    f32x4 wc = *(const f32x4*)(w_code + lane * 4 + j * 256);
    f32x4 y;
#pragma unroll
    for (int e = 0; e < 4; ++e) {
      y[e] = x[j][e] * inv;
      dot += (y[e] + r[e]) * wc[e];
    }
    *(f32x4*)(rp + lane * 4 + j * 256) = y;
  }
#pragma unroll
  for (int o = 32; o > 0; o >>= 1) dot += __shfl_xor(dot, o, 64);
  if (lane == 0) {
    float p = 1.f / (1.f + expf(-(dot + b_code[0])));
    code_probs[row] = (s < len_code[b]) ? p : 0.f;
  }
}

// ---------------- K5: sim via bf16 MFMA, 64x128 tiles, KC=64 (R9 proven) -----
__global__ __launch_bounds__(256) void k5_mfma(const float* __restrict__ nlh,
                                               const float* __restrict__ codeh,
                                               float* __restrict__ sim) {
  __shared__ unsigned short As[64 * 64];
  __shared__ unsigned short Bs[128 * 64];
  int id = blockIdx.x;
  int b = id & 63;
  int r = id >> 6;             // 0..9
  int nt = r % 2, ct = r / 2;  // nl half, code 128-tile
  int tid = threadIdx.x;
  int lane = tid & 63;
  int w = tid >> 6;
  int wm = w >> 1, wn = w & 1;  // wave: 32 nl x 64 code

  f32x4 acc[2][4];
#pragma unroll
  for (int m = 0; m < 2; ++m)
#pragma unroll
    for (int n = 0; n < 4; ++n) acc[m][n] = (f32x4){0.f, 0.f, 0.f, 0.f};

  const float* Ag = nlh + ((long)b * SN + nt * 64) * DD;
  const float* Bg = codeh + ((long)b * SC + ct * 128) * DD;

  for (int c = 0; c < DD / 64; ++c) {
#pragma unroll
    for (int it = 0; it < 4; ++it) {
      int i = tid + 256 * it;  // 0..1023
      int row = i >> 4, k0 = (i & 15) * 4;
      float4 va = *(const float4*)(Ag + (long)row * DD + c * 64 + k0);
      ushort4 ua = {f2bf(va.x), f2bf(va.y), f2bf(va.z), f2bf(va.w)};
      *(ushort4*)(&As[row * 64 + (k0 ^ ((row & 7) << 3))]) = ua;
    }
#pragma unroll
    for (int it = 0; it < 8; ++it) {
      int i = tid + 256 * it;  // 0..2047
      int row = i >> 4, k0 = (i & 15) * 4;
      float4 vb = *(const float4*)(Bg + (long)row * DD + c * 64 + k0);
      ushort4 ub = {f2bf(vb.x), f2bf(vb.y), f2bf(vb.z), f2bf(vb.w)};
      *(ushort4*)(&Bs[row * 64 + (k0 ^ ((row & 7) << 3))]) = ub;
    }
    __syncthreads();
#pragma unroll
    for (int ks = 0; ks < 2; ++ks) {
      int kb = ks * 32 + (lane >> 4) * 8;
      bf16x8 af[2], bfr[4];
#pragma unroll
      for (int m = 0; m < 2; ++m) {
        int rr = wm * 32 + m * 16 + (lane & 15);
        af[m] = *(const bf16x8*)(&As[rr * 64 + (kb ^ ((rr & 7) << 3))]);
      }
#pragma unroll
      for (int n = 0; n < 4; ++n) {
        int rr = wn * 64 + n * 16 + (lane & 15);
        bfr[n] = *(const bf16x8*)(&Bs[rr * 64 + (kb ^ ((rr & 7) << 3))]);
      }
#pragma unroll
      for (int m = 0; m < 2; ++m)
#pragma unroll
        for (int n = 0; n < 4; ++n)
          acc[m][n] = __builtin_amdgcn_mfma_f32_16x16x32_bf16(
              af[m], bfr[n], acc[m][n], 0, 0, 0);
    }
    __syncthreads();
  }
  long ob = ((long)b * SN + nt * 64) * SC + ct * 128;
#pragma unroll
  for (int m = 0; m < 2; ++m) {
    int row0 = wm * 32 + m * 16 + ((lane >> 4) << 2);
#pragma unroll
    for (int n = 0; n < 4; ++n) {
      int col = wn * 64 + n * 16 + (lane & 15);
#pragma unroll
      for (int rr = 0; rr < 4; ++rr)
        sim[ob + (long)(row0 + rr) * SC + col] = acc[m][n][rr];
    }
  }
}

// ---------------- launcher ---------------------------------------------------
extern "C" void kernel_launch(void* const* d_in, const int* in_sizes, int n_in,
                              void* d_out, int out_size, void* d_ws,
                              size_t ws_size, hipStream_t stream) {
  const int* code_ids = (const int*)d_in[0];
  const int* attn = (const int*)d_in[1];
  const int* pos = (const int*)d_in[2];
  const int* nl_ids = (const int*)d_in[3];
  const int* roles = (const int*)d_in[4];
  const float* Wemb = (const float*)d_in[5];
  const float* role_table = (const float*)d_in[6];
  const float* w_code = (const float*)d_in[7];
  const float* b_code = (const float*)d_in[8];
  const float* w_nl = (const float*)d_in[9];
  const float* b_nl = (const float*)d_in[10];

  float* out = (float*)d_out;
  float* codeh = out;                  // 64*640*768
  float* code_probs = out + 31457280;  // 64*640
  float* nlh = out + 31498240;         // 64*128*768
  float* nl_probs = out + 37789696;    // 64*128
  float* sim = out + 37797888;         // 64*128*640

  int* wsi = (int*)d_ws;
  int* len_code = wsi;  // 64

  k2_mfma<<<K2_BLOCKS + BB * SN / 4, 256, 0, stream>>>(
      code_ids, nl_ids, attn, pos, Wemb, codeh, len_code, w_nl, b_nl, nlh,
      nl_probs);
  k34_fused<<<CODE_BLOCKS, 256, 0, stream>>>(code_ids, pos, Wemb, codeh, roles,
                                             role_table, w_code, b_code,
                                             len_code, code_probs);
  k5_mfma<<<BB * 10, 256, 0, stream>>>(nlh, codeh, sim);
}

// Round 14
// 146.116 us; speedup vs baseline: 1.0778x; 1.0043x over previous
//
#include <hip/hip_runtime.h>

#define BB 64
#define SC 640
#define SN 128
#define DD 768
#define CODE_DEF 254
#define NL_DEF 126

typedef short bf16x8 __attribute__((ext_vector_type(8)));
typedef float f32x4 __attribute__((ext_vector_type(4)));

__device__ __forceinline__ unsigned short f2bf(float f) {
  unsigned u = __float_as_uint(f);
  u += 0x7fffu + ((u >> 16) & 1u);  // round-to-nearest-even
  return (unsigned short)(u >> 16);
}

#define K2_BLOCKS (BB * 24)

// ---------------- K2: node-avg GEMM + appended nl-branch blocks (R13) --------
__global__ __launch_bounds__(256) void k2_mfma(
    const int* __restrict__ code_ids, const int* __restrict__ nl_ids,
    const int* __restrict__ attn, const int* __restrict__ pos,
    const float* __restrict__ Wemb, float* __restrict__ codeh,
    int* __restrict__ len_code, const float* __restrict__ w_nl,
    const float* __restrict__ b_nl, float* __restrict__ nlh,
    float* __restrict__ nl_probs) {
  int id = blockIdx.x;
  if (id >= K2_BLOCKS) {  // ---------------- nl branch ----------------
    int w = threadIdx.x >> 6, lane = threadIdx.x & 63;
    long row = (long)(id - K2_BLOCKS) * 4 + w;
    int b = (int)(row / SN), s = (int)(row % SN);
    int firstn = NL_DEF;
    for (int c = 0; c < SN; c += 64) {
      unsigned long long m = __ballot(nl_ids[b * SN + c + lane] == 2);
      if (m) { firstn = c + __builtin_ctzll(m); break; }
    }
    const float* src = Wemb + (long)nl_ids[row] * DD;
    f32x4 x[3];
#pragma unroll
    for (int j = 0; j < 3; ++j)
      x[j] = *(const f32x4*)(src + lane * 4 + j * 256);
    float ss = 0.f;
#pragma unroll
    for (int j = 0; j < 3; ++j)
#pragma unroll
      for (int e = 0; e < 4; ++e) ss += x[j][e] * x[j][e];
#pragma unroll
    for (int o = 32; o > 0; o >>= 1) ss += __shfl_xor(ss, o, 64);
    float inv = 1.f / fmaxf(sqrtf(ss), 1e-12f);
    float* o = nlh + row * DD;
    float dot = 0.f;
#pragma unroll
    for (int j = 0; j < 3; ++j) {
      f32x4 wn = *(const f32x4*)(w_nl + lane * 4 + j * 256);
      f32x4 y;
#pragma unroll
      for (int e = 0; e < 4; ++e) {
        y[e] = x[j][e] * inv;
        dot += y[e] * wn[e];
      }
      *(f32x4*)(o + lane * 4 + j * 256) = y;
    }
#pragma unroll
    for (int of = 32; of > 0; of >>= 1) dot += __shfl_xor(dot, of, 64);
    if (lane == 0) {
      float p = 1.f / (1.f + expf(-(dot + b_nl[0])));
      nl_probs[row] = (s < firstn) ? p : 0.f;
    }
    return;
  }
  // ---------------- node-avg GEMM (R11 proven) ----------------
  __shared__ unsigned short As[2][64 * 64];
  __shared__ unsigned short Bs[2][128 * 64];
  __shared__ int rowsidx[64];
  __shared__ int cid[SC];
  __shared__ unsigned long long tokm[10];
  __shared__ float cnts_l[64];
  __shared__ int cnt_s, flag_s;
  int b = id & 63;   // same-b -> same XCD (stride 64)
  int g = id >> 6;   // 0..23
  int nt = g & 3, dt = g >> 2;  // 4 node-tiles x 6 d-tiles
  int tid = threadIdx.x;
  const int lane = tid & 63, w = tid >> 6, wm = w >> 1, wn = w & 1;
  for (int i = tid; i < SC; i += 256) cid[i] = code_ids[b * SC + i];
  if (tid < 64) rowsidx[tid] = -1;  // w0's own lanes, program-order safe
  if (w == 0) {  // node compaction, keep slots in [nt*64, nt*64+64)
    int base = 0;
    for (int c = 0; c < 10; ++c) {
      bool isn = pos[b * SC + c * 64 + lane] == 0;
      unsigned long long m = __ballot(isn);
      int pre = __popcll(m & ((1ull << lane) - 1ull));
      int slot = base + pre;
      if (isn && slot >= nt * 64 && slot < nt * 64 + 64)
        rowsidx[slot - nt * 64] = c * 64 + lane;
      base += __popcll(m);
    }
    if (lane == 0) cnt_s = base;
  } else if (w == 1) {  // token-mask bits
    for (int k = 0; k < 10; ++k) {
      unsigned long long m = __ballot(pos[b * SC + k * 64 + lane] >= 2);
      if (lane == 0) tokm[k] = m;
    }
  } else if (w == 2) {  // attn dtype detect (first 4KB, L2-hot)
    int bad = 0;
    for (int i = lane; i < 1024; i += 64)
      if (((const unsigned*)attn)[i] > 1u) bad = 1;
    unsigned long long m = __ballot(bad);
    if (lane == 0) flag_s = (m != 0ull) ? 1 : 0;
  } else if (g == 0) {  // w==3: eos len for k34 code branch
    int first = CODE_DEF;
    for (int c = 0; c < SC; c += 64) {
      unsigned long long m = __ballot(code_ids[b * SC + c + lane] == 2);
      if (m) { first = c + __builtin_ctzll(m); break; }
    }
    if (lane == 0) len_code[b] = first;
  }
  __syncthreads();
  const int count = cnt_s;
  if (nt * 64 >= count) return;
  const int dcol = dt * 128;
  const int isu8 = flag_s;

  f32x4 acc[2][4];
#pragma unroll
  for (int m = 0; m < 2; ++m)
#pragma unroll
    for (int n = 0; n < 4; ++n) acc[m][n] = (f32x4){0.f, 0.f, 0.f, 0.f};

  const int r_a = tid >> 2, q_ = tid & 3;  // A: row 0..63, 16-t quarter 0..3
  const int nrow_a = rowsidx[r_a];
  const long arow = (nrow_a >= 0) ? ((long)b * SC + nrow_a) * SC : 0;
  const unsigned char* attn_u8 = (const unsigned char*)attn;
  int ptot = 0;
  int tg4[2], d0[2];
#pragma unroll
  for (int q = 0; q < 2; ++q) {
    int task = tid + 256 * q;
    tg4[q] = task >> 5;       // 0..15
    d0[q] = (task & 31) * 4;  // 0..124
  }

  f32x4 va[2][4];
  unsigned bits16;

#define LOADC(cc)                                                          \
  {                                                                        \
    unsigned tokq = (unsigned)((tokm[cc] >> (q_ * 16)) & 0xffffull);       \
    unsigned ab = 0;                                                       \
    if (nrow_a >= 0) {                                                     \
      if (isu8) {                                                          \
        uint4 v = *(const uint4*)(attn_u8 + arow + (cc) * 64 + q_ * 16);   \
        _Pragma("unroll") for (int j = 0; j < 4; ++j) {                    \
          ab |= (((v.x >> (8 * j)) & 0xffu) ? 1u : 0u) << j;               \
          ab |= (((v.y >> (8 * j)) & 0xffu) ? 1u : 0u) << (4 + j);         \
          ab |= (((v.z >> (8 * j)) & 0xffu) ? 1u : 0u) << (8 + j);         \
          ab |= (((v.w >> (8 * j)) & 0xffu) ? 1u : 0u) << (12 + j);        \
        }                                                                  \
      } else {                                                             \
        const int* ap = attn + arow + (cc) * 64 + q_ * 16;                 \
        _Pragma("unroll") for (int j = 0; j < 4; ++j) {                    \
          int4 v = *(const int4*)(ap + j * 4);                             \
          ab |= (v.x ? 1u : 0u) << (4 * j);                                \
          ab |= (v.y ? 1u : 0u) << (4 * j + 1);                            \
          ab |= (v.z ? 1u : 0u) << (4 * j + 2);                            \
          ab |= (v.w ? 1u : 0u) << (4 * j + 3);                            \
        }                                                                  \
      }                                                                    \
    }                                                                      \
    bits16 = ab & tokq;                                                    \
    ptot += __popc(bits16);                                                \
    _Pragma("unroll") for (int q = 0; q < 2; ++q)                          \
        _Pragma("unroll") for (int j = 0; j < 4; ++j) va[q][j] =           \
        *(const f32x4*)(Wemb +                                             \
                        (long)cid[(cc) * 64 + tg4[q] * 4 + j] * DD +       \
                        dcol + d0[q]);                                     \
  }

#define WRITEB(bf_)                                                        \
  {                                                                        \
    unsigned short* Ab = As[bf_];                                          \
    unsigned short* Bb = Bs[bf_];                                          \
    int tl = q_ * 16, sw = (r_a & 7) << 3;                                 \
    bf16x8 u0, u1;                                                         \
    _Pragma("unroll") for (int j = 0; j < 8; ++j) {                        \
      u0[j] = ((bits16 >> j) & 1u) ? (short)0x3F80 : (short)0;             \
      u1[j] = ((bits16 >> (8 + j)) & 1u) ? (short)0x3F80 : (short)0;       \
    }                                                                      \
    *(bf16x8*)(&Ab[r_a * 64 + (tl ^ sw)]) = u0;                            \
    *(bf16x8*)(&Ab[r_a * 64 + ((tl + 8) ^ sw)]) = u1;                      \
    _Pragma("unroll") for (int q = 0; q < 2; ++q)                          \
        _Pragma("unroll") for (int dj = 0; dj < 4; ++dj) {                 \
      int d = d0[q] + dj;                                                  \
      ushort4 u = {f2bf(va[q][0][dj]), f2bf(va[q][1][dj]),                 \
                   f2bf(va[q][2][dj]), f2bf(va[q][3][dj])};                \
      int s = ((((d >> 2) & 7) ^ ((d & 3) << 1)) << 3);                    \
      *(ushort4*)(&Bb[d * 64 + ((tg4[q] * 4) ^ s)]) = u;                   \
    }                                                                      \
  }

#define MFMAP(bf_)                                                         \
  {                                                                        \
    const unsigned short* Ab = As[bf_];                                    \
    const unsigned short* Bb = Bs[bf_];                                    \
    _Pragma("unroll") for (int ks = 0; ks < 2; ++ks) {                     \
      int kb = ks * 32 + (lane >> 4) * 8;                                  \
      bf16x8 af[2], bfv[4];                                                \
      _Pragma("unroll") for (int m = 0; m < 2; ++m) {                      \
        int rr = wm * 32 + m * 16 + (lane & 15);                           \
        af[m] = *(const bf16x8*)(&Ab[rr * 64 + (kb ^ ((rr & 7) << 3))]);   \
      }                                                                    \
      _Pragma("unroll") for (int n = 0; n < 4; ++n) {                      \
        int cc = wn * 64 + n * 16 + (lane & 15);                           \
        int s = ((((cc >> 2) & 7) ^ ((cc & 3) << 1)) << 3);                \
        bfv[n] = *(const bf16x8*)(&Bb[cc * 64 + (kb ^ s)]);                \
      }                                                                    \
      _Pragma("unroll") for (int m = 0; m < 2; ++m)                        \
          _Pragma("unroll") for (int n = 0; n < 4; ++n) acc[m][n] =        \
          __builtin_amdgcn_mfma_f32_16x16x32_bf16(af[m], bfv[n],           \
                                                  acc[m][n], 0, 0, 0);     \
    }                                                                      \
  }

  LOADC(0);
  WRITEB(0);
  __syncthreads();
  for (int c = 0; c < 10; ++c) {
    if (c < 9) LOADC(c + 1);
    MFMAP(c & 1);
    if (c < 9) WRITEB((c + 1) & 1);
    __syncthreads();
  }

  {
    int t4 = ptot + __shfl_xor(ptot, 1, 64);
    t4 += __shfl_xor(t4, 2, 64);
    if (q_ == 0) cnts_l[r_a] = (float)t4;
  }
  __syncthreads();

  float* outb = codeh + (long)b * SC * DD + dcol + wn * 64;
#pragma unroll
  for (int m = 0; m < 2; ++m) {
    int row0 = wm * 32 + m * 16 + ((lane >> 4) << 2);
#pragma unroll
    for (int rr2 = 0; rr2 < 4; ++rr2) {
      int slotr = row0 + rr2;
      int nr = rowsidx[slotr];
      if (nr < 0) continue;
      float cnt = cnts_l[slotr];
      float inv = (cnt > 0.f) ? 1.f / cnt : 0.f;
      float* orow = outb + (long)nr * DD;
#pragma unroll
      for (int n = 0; n < 4; ++n)
        orow[n * 16 + (lane & 15)] = acc[m][n][rr2] * inv;
    }
  }
#undef LOADC
#undef WRITEB
#undef MFMAP
}

// ---------------- K34: code-finish only, 1 row per wave (R11 proven) ---------
#define CODE_BLOCKS (BB * SC / 4)
__global__ __launch_bounds__(256) void k34_fused(
    const int* __restrict__ code_ids, const int* __restrict__ pos,
    const float* __restrict__ Wemb, float* __restrict__ codeh,
    const int* __restrict__ roles, const float* __restrict__ role_table,
    const float* __restrict__ w_code, const float* __restrict__ b_code,
    const int* __restrict__ len_code, float* __restrict__ code_probs) {
  int w = threadIdx.x >> 6, lane = threadIdx.x & 63;
  long row = (long)blockIdx.x * 4 + w;
  int b = (int)(row / SC), s = (int)(row % SC);
  float* rp = codeh + row * DD;
  const float* src = (pos[row] == 0) ? rp : (Wemb + (long)code_ids[row] * DD);
  f32x4 x[3];
#pragma unroll
  for (int j = 0; j < 3; ++j)
    x[j] = *(const f32x4*)(src + lane * 4 + j * 256);
  float ss = 0.f;
#pragma unroll
  for (int j = 0; j < 3; ++j)
#pragma unroll
    for (int e = 0; e < 4; ++e) ss += x[j][e] * x[j][e];
#pragma unroll
  for (int o = 32; o > 0; o >>= 1) ss += __shfl_xor(ss, o, 64);
  float inv = 1.f / fmaxf(sqrtf(ss), 1e-12f);
  const float* rt = role_table + (long)roles[row] * DD;
  float dot = 0.f;
#pragma unroll
  for (int j = 0; j < 3; ++j) {
    f32x4 r = *(const f32x4*)(rt + lane * 4 + j * 256);
    f32x4 wc = *(const f32x4*)(w_code + lane * 4 + j * 256);
    f32x4 y;
#pragma unroll
    for (int e = 0; e < 4; ++e) {
      y[e] = x[j][e] * inv;
      dot += (y[e] + r[e]) * wc[e];
    }
    *(f32x4*)(rp + lane * 4 + j * 256) = y;
  }
#pragma unroll
  for (int o = 32; o > 0; o >>= 1) dot += __shfl_xor(dot, o, 64);
  if (lane == 0) {
    float p = 1.f / (1.f + expf(-(dot + b_code[0])));
    code_probs[row] = (s < len_code[b]) ? p : 0.f;
  }
}

// ---------------- K5: sim via bf16 MFMA, reg-prefetch double-buffer ----------
// Same 64x128 tile / KC=64 as R9, but k2's proven pipeline: LOAD5(c+1) regs ->
// MFMA(c) -> WRITE5(c+1) -> one barrier. Hides L2-hot load latency under MFMA.
__global__ __launch_bounds__(256) void k5_mfma(const float* __restrict__ nlh,
                                               const float* __restrict__ codeh,
                                               float* __restrict__ sim) {
  __shared__ unsigned short As[2][64 * 64];
  __shared__ unsigned short Bs[2][128 * 64];
  int id = blockIdx.x;
  int b = id & 63;
  int r = id >> 6;             // 0..9
  int nt = r % 2, ct = r / 2;  // nl half, code 128-tile
  int tid = threadIdx.x;
  int lane = tid & 63;
  int w = tid >> 6;
  int wm = w >> 1, wn = w & 1;  // wave: 32 nl x 64 code

  f32x4 acc[2][4];
#pragma unroll
  for (int m = 0; m < 2; ++m)
#pragma unroll
    for (int n = 0; n < 4; ++n) acc[m][n] = (f32x4){0.f, 0.f, 0.f, 0.f};

  const float* Ag = nlh + ((long)b * SN + nt * 64) * DD;
  const float* Bg = codeh + ((long)b * SC + ct * 128) * DD;

  f32x4 vA[4], vB[8];

#define LOAD5(cc)                                                          \
  {                                                                        \
    _Pragma("unroll") for (int it = 0; it < 4; ++it) {                     \
      int i = tid + 256 * it;                                              \
      int row = i >> 4, k0 = (i & 15) * 4;                                 \
      vA[it] = *(const f32x4*)(Ag + (long)row * DD + (cc) * 64 + k0);      \
    }                                                                      \
    _Pragma("unroll") for (int it = 0; it < 8; ++it) {                     \
      int i = tid + 256 * it;                                              \
      int row = i >> 4, k0 = (i & 15) * 4;                                 \
      vB[it] = *(const f32x4*)(Bg + (long)row * DD + (cc) * 64 + k0);      \
    }                                                                      \
  }

#define WRITE5(bf_)                                                        \
  {                                                                        \
    unsigned short* Ab = As[bf_];                                          \
    unsigned short* Bb = Bs[bf_];                                          \
    _Pragma("unroll") for (int it = 0; it < 4; ++it) {                     \
      int i = tid + 256 * it;                                              \
      int row = i >> 4, k0 = (i & 15) * 4;                                 \
      ushort4 ua = {f2bf(vA[it][0]), f2bf(vA[it][1]), f2bf(vA[it][2]),     \
                    f2bf(vA[it][3])};                                      \
      *(ushort4*)(&Ab[row * 64 + (k0 ^ ((row & 7) << 3))]) = ua;           \
    }                                                                      \
    _Pragma("unroll") for (int it = 0; it < 8; ++it) {                     \
      int i = tid + 256 * it;                                              \
      int row = i >> 4, k0 = (i & 15) * 4;                                 \
      ushort4 ub = {f2bf(vB[it][0]), f2bf(vB[it][1]), f2bf(vB[it][2]),     \
                    f2bf(vB[it][3])};                                      \
      *(ushort4*)(&Bb[row * 64 + (k0 ^ ((row & 7) << 3))]) = ub;           \
    }                                                                      \
  }

#define MFMA5(bf_)                                                         \
  {                                                                        \
    const unsigned short* Ab = As[bf_];                                    \
    const unsigned short* Bb = Bs[bf_];                                    \
    _Pragma("unroll") for (int ks = 0; ks < 2; ++ks) {                     \
      int kb = ks * 32 + (lane >> 4) * 8;                                  \
      bf16x8 af[2], bfr[4];                                                \
      _Pragma("unroll") for (int m = 0; m < 2; ++m) {                      \
        int rr = wm * 32 + m * 16 + (lane & 15);                           \
        af[m] = *(const bf16x8*)(&Ab[rr * 64 + (kb ^ ((rr & 7) << 3))]);   \
      }                                                                    \
      _Pragma("unroll") for (int n = 0; n < 4; ++n) {                      \
        int rr = wn * 64 + n * 16 + (lane & 15);                           \
        bfr[n] = *(const bf16x8*)(&Bs[bf_][rr * 64 + (kb ^ ((rr & 7) << 3))]); \
      }                                                                    \
      (void)Bb;                                                            \
      _Pragma("unroll") for (int m = 0; m < 2; ++m)                        \
          _Pragma("unroll") for (int n = 0; n < 4; ++n) acc[m][n] =        \
          __builtin_amdgcn_mfma_f32_16x16x32_bf16(af[m], bfr[n],           \
                                                  acc[m][n], 0, 0, 0);     \
    }                                                                      \
  }

  LOAD5(0);
  WRITE5(0);
  __syncthreads();
  for (int c = 0; c < DD / 64; ++c) {
    if (c < DD / 64 - 1) LOAD5(c + 1);
    MFMA5(c & 1);
    if (c < DD / 64 - 1) WRITE5((c + 1) & 1);
    __syncthreads();
  }
#undef LOAD5
#undef WRITE5
#undef MFMA5

  long ob = ((long)b * SN + nt * 64) * SC + ct * 128;
#pragma unroll
  for (int m = 0; m < 2; ++m) {
    int row0 = wm * 32 + m * 16 + ((lane >> 4) << 2);
#pragma unroll
    for (int n = 0; n < 4; ++n) {
      int col = wn * 64 + n * 16 + (lane & 15);
#pragma unroll
      for (int rr = 0; rr < 4; ++rr)
        sim[ob + (long)(row0 + rr) * SC + col] = acc[m][n][rr];
    }
  }
}

// ---------------- launcher ---------------------------------------------------
extern "C" void kernel_launch(void* const* d_in, const int* in_sizes, int n_in,
                              void* d_out, int out_size, void* d_ws,
                              size_t ws_size, hipStream_t stream) {
  const int* code_ids = (const int*)d_in[0];
  const int* attn = (const int*)d_in[1];
  const int* pos = (const int*)d_in[2];
  const int* nl_ids = (const int*)d_in[3];
  const int* roles = (const int*)d_in[4];
  const float* Wemb = (const float*)d_in[5];
  const float* role_table = (const float*)d_in[6];
  const float* w_code = (const float*)d_in[7];
  const float* b_code = (const float*)d_in[8];
  const float* w_nl = (const float*)d_in[9];
  const float* b_nl = (const float*)d_in[10];

  float* out = (float*)d_out;
  float* codeh = out;                  // 64*640*768
  float* code_probs = out + 31457280;  // 64*640
  float* nlh = out + 31498240;         // 64*128*768
  float* nl_probs = out + 37789696;    // 64*128
  float* sim = out + 37797888;         // 64*128*640

  int* wsi = (int*)d_ws;
  int* len_code = wsi;  // 64

  k2_mfma<<<K2_BLOCKS + BB * SN / 4, 256, 0, stream>>>(
      code_ids, nl_ids, attn, pos, Wemb, codeh, len_code, w_nl, b_nl, nlh,
      nl_probs);
  k34_fused<<<CODE_BLOCKS, 256, 0, stream>>>(code_ids, pos, Wemb, codeh, roles,
                                             role_table, w_code, b_code,
                                             len_code, code_probs);
  k5_mfma<<<BB * 10, 256, 0, stream>>>(nlh, codeh, sim);
}